// Round 6
// baseline (56.540 us; speedup 1.0000x reference)
//
#include <hip/hip_runtime.h>
#include <math.h>

#define S_    10
#define C_    48
#define HWD   64
#define M_    512
#define PADK  4
#define PAIRS 20           // S_ * N(=2)
#define YPITCH 516         // LDS pitch (516%32=4 -> only 2-way bank alias = free)

// Compact gathered y layout: G[(s*96 + 2*c + n)*512 + m]
// ws layout (float offsets)
#define OFF_GY  0
#define OFF_CM  491520                    // colmax (uint-encoded floats), 10240
#define OFF_MU  (OFF_CM + PAIRS * M_)     // 480 floats
#define OFF_CNT (OFF_MU + 480)            // 20 uint pair-arrival counters
#define OFF_ALL (OFF_CNT + 20)            // 1 uint global pair-done counter
#define OFF_PL  (OFF_ALL + 1)             // 20 float pair losses

__device__ __forceinline__ int gidx(int n, int c, int h, int w, int d) {
  return (((n * C_ + c) * HWD + h) * HWD + w) * HWD + d;
}

// ---- kernel 1: gather y -> compact ws + per-(s,c) mean; zero accumulators -
// 480 blocks x 256 thr; block = (s,c); 4 elements/thread (max MLP).
__global__ void k_gy(const float* __restrict__ y, const int* __restrict__ hi,
                     const int* __restrict__ wi, const int* __restrict__ di,
                     float* __restrict__ ws) {
  int b = blockIdx.x, t = threadIdx.x;
  int lane = t & 63, wv = t >> 6;
  if (b < 40) ws[OFF_CM + b * 256 + t] = 0.f;        // zero colmax (10240)
  if (b == 40 && t < 41) ws[OFF_CNT + t] = 0.f;      // zero counters + losses
  int s = b / C_, c = b % C_;
  int h0 = hi[s] - PADK, w0 = wi[s] - PADK, d0 = di[s] - PADK;
  float* dst = ws + OFF_GY + (s * 96 + 2 * c) * 512;
  float sum = 0.f;
#pragma unroll
  for (int j = 0; j < 4; ++j) {
    int i = t + 256 * j;             // 0..1023 over (n,m)
    int n = i >> 9, m = i & 511;
    float v = y[gidx(n, c, h0 + (m >> 6), w0 + ((m >> 3) & 7), d0 + (m & 7))];
    dst[n * 512 + m] = v;            // coalesced compact store
    sum += v;
  }
#pragma unroll
  for (int off = 32; off; off >>= 1) sum += __shfl_xor(sum, off);
  __shared__ float red[4];
  if (lane == 0) red[wv] = sum;
  __syncthreads();
  if (t == 0)
    ws[OFF_MU + s * C_ + c] =
        (red[0] + red[1] + red[2] + red[3]) * (1.0f / 1024.0f);
}

// ---- kernel 2: center + L2-normalize compact y in place (L2-resident) ----
// 160 blocks x 256 thr; 4 lanes per column (12 channels each).
__global__ void k_ny(float* __restrict__ ws) {
  int g = blockIdx.x * 256 + threadIdx.x;   // 0..40959
  int col = g >> 2;                         // 0..10239
  int q = threadIdx.x & 3;                  // channel quarter
  int pair = col >> 9, m = col & 511;
  int s = pair >> 1, n = pair & 1;
  float* base = ws + OFF_GY + (s * 96 + n) * 512 + m;
  const float* mus = ws + OFF_MU + s * C_;
  int c0 = q * 12;
  float v[12], ss = 0.f;
#pragma unroll
  for (int j = 0; j < 12; ++j) {
    v[j] = base[(c0 + j) * 1024] - mus[c0 + j];
    ss += v[j] * v[j];
  }
  ss += __shfl_xor(ss, 1);           // combine 4 quarters (aligned group)
  ss += __shfl_xor(ss, 2);
  float sc = 1.0f / fmaxf(sqrtf(ss), 1e-12f);
#pragma unroll
  for (int j = 0; j < 12; ++j) base[(c0 + j) * 1024] = v[j] * sc;
}

// ---- kernel 3: stage+normalize raw x tile; dist+softmax+colmax+final ------
// 320 blocks x 256 thr; block = (pair, tile of 32 rows); 8 rows/wave.
__global__ __launch_bounds__(256, 4) void k_main(const float* __restrict__ x,
                                                 const int* __restrict__ hi,
                                                 const int* __restrict__ wi,
                                                 const int* __restrict__ di,
                                                 float* __restrict__ ws,
                                                 float* __restrict__ out) {
  int b = blockIdx.x;
  int pair = b >> 4, tile = b & 15;
  int s = pair >> 1, n = pair & 1;
  int t = threadIdx.x, lane = t & 63, wv = t >> 6;

  __shared__ float xl[C_ * 32];        // x tile: [c][row] (32 rows)
  __shared__ float yl[12 * YPITCH];    // y chunk: [c_rel][p]; pl/scv alias it
  __shared__ float mus[C_];
  float* pl = yl;                      // [8][32] column-ss partials (alias)
  float* scv = yl + 256;               // [32] per-column scales (alias)

  // stage RAW x tile: li -> (c = li>>5, r = li&31), m = tile*32 + r
  int h0 = hi[s] - PADK, w0 = wi[s] - PADK, d0 = di[s] - PADK;
  if (t < C_) mus[t] = ws[OFF_MU + s * C_ + t];
#pragma unroll
  for (int i = 0; i < 6; ++i) {
    int li = t + 256 * i;              // 0..1535
    int c = li >> 5, r = li & 31;
    int m = tile * 32 + r;
    xl[c * 32 + r] =
        x[gidx(n, c, h0 + (m >> 6), w0 + ((m >> 3) & 7), d0 + (m & 7))];
  }
  __syncthreads();

  // center + per-column sum-of-squares (8 groups x 6 channels, col = t&31)
  int grp = t >> 5, col = t & 31;
  {
    float ss = 0.f;
#pragma unroll
    for (int cc = 0; cc < 6; ++cc) {
      int c = grp * 6 + cc;
      float v = xl[c * 32 + col] - mus[c];
      xl[c * 32 + col] = v;
      ss += v * v;
    }
    pl[grp * 32 + col] = ss;
  }
  __syncthreads();
  if (t < 32) {
    float tot = 0.f;
#pragma unroll
    for (int g = 0; g < 8; ++g) tot += pl[g * 32 + t];
    scv[t] = 1.0f / fmaxf(sqrtf(tot), 1e-12f);
  }
  __syncthreads();
  {
    float sc = scv[col];
#pragma unroll
    for (int cc = 0; cc < 6; ++cc) {
      int c = grp * 6 + cc;
      xl[c * 32 + col] *= sc;
    }
  }
  // NOTE: yl (aliased by pl/scv) is overwritten only after the next sync.

  float acc[8][8];
#pragma unroll
  for (int r = 0; r < 8; ++r)
#pragma unroll
    for (int k = 0; k < 8; ++k) acc[r][k] = 0.f;

  const float* ysrc = ws + OFF_GY + (s * 96 + n) * 512;
  for (int chunk = 0; chunk < 4; ++chunk) {
    __syncthreads();                   // covers xl rescale + prev-chunk reads
#pragma unroll
    for (int i = 0; i < 6; ++i) {      // 12 channels x 512 = 1536 float4s
      int li = t + 256 * i;
      int cr = li >> 7, p4 = (li & 127) << 2;
      *(float4*)(yl + cr * YPITCH + p4) =
          *(const float4*)(ysrc + (chunk * 12 + cr) * 1024 + p4);
    }
    __syncthreads();
#pragma unroll
    for (int cr = 0; cr < 12; ++cr) {
      float yv[8];
#pragma unroll
      for (int k = 0; k < 8; ++k) yv[k] = yl[cr * YPITCH + lane + 64 * k];
      int c = chunk * 12 + cr;
#pragma unroll
      for (int r4 = 0; r4 < 2; ++r4) {
        float4 xv = *(const float4*)(xl + c * 32 + wv * 8 + r4 * 4); // broadcast
#pragma unroll
        for (int k = 0; k < 8; ++k) {
          acc[r4 * 4 + 0][k] += xv.x * yv[k];
          acc[r4 * 4 + 1][k] += xv.y * yv[k];
          acc[r4 * 4 + 2][k] += xv.z * yv[k];
          acc[r4 * 4 + 3][k] += xv.w * yv[k];
        }
      }
    }
  }

  // epilogue: per row min -> softmax over p -> column-max accumulate
  float cmax[8];
#pragma unroll
  for (int k = 0; k < 8; ++k) cmax[k] = 0.f;
#pragma unroll
  for (int r = 0; r < 8; ++r) {
    float dmin = 3.4e38f;
#pragma unroll
    for (int k = 0; k < 8; ++k) {
      float d = 1.0f - acc[r][k];
      acc[r][k] = d;
      dmin = fminf(dmin, d);
    }
#pragma unroll
    for (int off = 32; off; off >>= 1) dmin = fminf(dmin, __shfl_xor(dmin, off));
    float inv = 2.0f / (dmin + 1e-5f); // logits <= 2, no overflow
    float e[8], sm = 0.f;
#pragma unroll
    for (int k = 0; k < 8; ++k) {
      e[k] = __expf(2.0f - acc[r][k] * inv);
      sm += e[k];
    }
#pragma unroll
    for (int off = 32; off; off >>= 1) sm += __shfl_xor(sm, off);
    float rs = 1.0f / sm;
#pragma unroll
    for (int k = 0; k < 8; ++k) cmax[k] = fmaxf(cmax[k], e[k] * rs);
  }
  unsigned* cmu = (unsigned*)(ws + OFF_CM) + pair * M_;
#pragma unroll
  for (int k = 0; k < 8; ++k)
    atomicMax(&cmu[lane + 64 * k], __float_as_uint(cmax[k]));

  // ---- fused final: last block per pair reduces; last pair writes out ----
  __threadfence();
  __shared__ unsigned arr;
  __shared__ float red[4];
  __shared__ int lastflag;
  if (t == 0) arr = atomicAdd((unsigned*)(ws + OFF_CNT) + pair, 1u);
  __syncthreads();
  if (arr == 15) {
    float sum = __uint_as_float(atomicOr(&cmu[t], 0u)) +
                __uint_as_float(atomicOr(&cmu[t + 256], 0u));
#pragma unroll
    for (int off = 32; off; off >>= 1) sum += __shfl_xor(sum, off);
    if (lane == 0) red[wv] = sum;
    if (t == 0) lastflag = 0;
    __syncthreads();
    if (t == 0) {
      float tot = red[0] + red[1] + red[2] + red[3];
      float loss = -logf(tot * (1.0f / 512.0f) + 1e-5f);
      atomicExch((unsigned*)(ws + OFF_PL) + pair, __float_as_uint(loss));
      __threadfence();
      unsigned d = atomicAdd((unsigned*)(ws + OFF_ALL), 1u);
      if (d == PAIRS - 1) lastflag = 1;
    }
    __syncthreads();
    if (lastflag && t < 32) {          // parallel 20-loss readback
      float v = (t < PAIRS)
                    ? __uint_as_float(atomicOr((unsigned*)(ws + OFF_PL) + t, 0u))
                    : 0.f;
#pragma unroll
      for (int off = 16; off; off >>= 1) v += __shfl_xor(v, off);
      if (t == 0) out[0] = v * (1.0f / (float)PAIRS);
    }
  }
}

extern "C" void kernel_launch(void* const* d_in, const int* in_sizes, int n_in,
                              void* d_out, int out_size, void* d_ws, size_t ws_size,
                              hipStream_t stream) {
  const float* x = (const float*)d_in[0];
  const float* y = (const float*)d_in[1];
  const int* hi = (const int*)d_in[2];
  const int* wi = (const int*)d_in[3];
  const int* di = (const int*)d_in[4];
  float* ws = (float*)d_ws;
  float* out = (float*)d_out;

  k_gy<<<S_ * C_, 256, 0, stream>>>(y, hi, wi, di, ws);
  k_ny<<<160, 256, 0, stream>>>(ws);
  k_main<<<PAIRS * 16, 256, 0, stream>>>(x, hi, wi, di, ws, out);
}